// Round 6
// baseline (480.992 us; speedup 1.0000x reference)
//
#include <hip/hip_runtime.h>
#include <hip/hip_bf16.h>

// B=128, C=20000, F=64, K=32.
// Outputs flat-concat: fa [B*C*64] | ca [B*C] | mean [B] | pred [B], all f32.

#define EPS_DENOM 1e-10f

typedef float floatx4 __attribute__((ext_vector_type(4)));

// ---------------------------------------------------------------------------
// Kernel A: case activations only (10 MB out). Numerics verbatim from the
// passing round-1 kernel: 16 lanes per case, per-group dot, shfl-xor tree.
// ---------------------------------------------------------------------------
__global__ __launch_bounds__(256) void ca_kernel(
    const float* __restrict__ q,
    const float* __restrict__ cases,
    const float* __restrict__ w_fa,
    const float* __restrict__ b_fa,
    const float* __restrict__ w_ca,
    const float* __restrict__ b_ca,
    float* __restrict__ ca_out,
    int B, int C)
{
    const int g = threadIdx.x & 15;   // feature group (features g*4 .. g*4+3)
    const int p = threadIdx.x >> 4;   // case slot 0..15
    const int c = blockIdx.x * 16 + p;
    const int b = blockIdx.y;
    if (c >= C) return;

    const int f4 = g * 4;
    const float4 qv = *reinterpret_cast<const float4*>(q     + (size_t)b * 64 + f4);
    const float4 cv = *reinterpret_cast<const float4*>(cases + (size_t)c * 64 + f4);
    const float4 wf = *reinterpret_cast<const float4*>(w_fa + f4);
    const float4 bf = *reinterpret_cast<const float4*>(b_fa + f4);
    const float4 wc = *reinterpret_cast<const float4*>(w_ca + f4);

    float d0 = qv.x - cv.x, d1 = qv.y - cv.y, d2 = qv.z - cv.z, d3 = qv.w - cv.w;
    float s0 = 1.0f / (1.0f + __expf(fmaf(d0 * d0, wf.x, -bf.x)));
    float s1 = 1.0f / (1.0f + __expf(fmaf(d1 * d1, wf.y, -bf.y)));
    float s2 = 1.0f / (1.0f + __expf(fmaf(d2 * d2, wf.z, -bf.z)));
    float s3 = 1.0f / (1.0f + __expf(fmaf(d3 * d3, wf.w, -bf.w)));

    float dot = s0 * wc.x + s1 * wc.y + s2 * wc.z + s3 * wc.w;
    dot += __shfl_xor(dot, 1, 64);
    dot += __shfl_xor(dot, 2, 64);
    dot += __shfl_xor(dot, 4, 64);
    dot += __shfl_xor(dot, 8, 64);

    if (g == 0) {
        float cav = 1.0f / (1.0f + __expf(-(dot + b_ca[0])));
        ca_out[(size_t)b * C + c] = cav;  // raw; topk rewrites in place
    }
}

// ---------------------------------------------------------------------------
// Kernel B: feature_activations streamer, round-4 shape (one query per block,
// 64 cases per block, x-major dispatch order => compact sequential write
// window). SINGLE CHANGE vs round 4: regular write-back stores, not NT.
// ---------------------------------------------------------------------------
__global__ __launch_bounds__(256) void fa_kernel(
    const float* __restrict__ q,
    const float* __restrict__ cases,
    const float* __restrict__ w_fa,
    const float* __restrict__ b_fa,
    float* __restrict__ fa_out,
    int B, int C)
{
    const int g  = threadIdx.x & 15;
    const int p  = threadIdx.x >> 4;
    const int b  = blockIdx.y;
    const int c0 = blockIdx.x * 64 + p;
    const int f4 = g * 4;

    const float4 qv = *reinterpret_cast<const float4*>(q    + (size_t)b * 64 + f4);
    const float4 wf = *reinterpret_cast<const float4*>(w_fa + f4);
    const float4 bf = *reinterpret_cast<const float4*>(b_fa + f4);

    float4 cv[4];
    #pragma unroll
    for (int j = 0; j < 4; ++j) {
        int c = c0 + j * 16;
        if (c > C - 1) c = C - 1;  // clamp: load stays valid, store is guarded
        cv[j] = *reinterpret_cast<const float4*>(cases + (size_t)c * 64 + f4);
    }

    #pragma unroll
    for (int j = 0; j < 4; ++j) {
        const int c = c0 + j * 16;
        if (c < C) {
            float d0 = qv.x - cv[j].x, d1 = qv.y - cv[j].y;
            float d2 = qv.z - cv[j].z, d3 = qv.w - cv[j].w;
            float s0 = 1.0f / (1.0f + __expf(fmaf(d0 * d0, wf.x, -bf.x)));
            float s1 = 1.0f / (1.0f + __expf(fmaf(d1 * d1, wf.y, -bf.y)));
            float s2 = 1.0f / (1.0f + __expf(fmaf(d2 * d2, wf.z, -bf.z)));
            float s3 = 1.0f / (1.0f + __expf(fmaf(d3 * d3, wf.w, -bf.w)));
            floatx4 sv = { s0, s1, s2, s3 };
            *reinterpret_cast<floatx4*>(
                fa_out + ((size_t)b * C + c) * 64 + f4) = sv;   // regular store
        }
    }
}

// ---------------------------------------------------------------------------
// Kernel C: per-row exact top-K via radix select (plain LDS-atomic histogram
// — wave-aggregation measured 15x WORSE in round 4), then normalize in place
// + scalar outputs. One block per query row.
// ---------------------------------------------------------------------------
#define TPB2 256

__global__ __launch_bounds__(TPB2) void topk_kernel(
    float* __restrict__ ca,
    const float* __restrict__ labels,
    float* __restrict__ out_mean,
    float* __restrict__ out_pred,
    int C, const int* __restrict__ kp)
{
    __shared__ unsigned int hist[256];
    __shared__ unsigned int s_bsel;
    __shared__ int s_cum;
    __shared__ float s_red[TPB2];
    __shared__ float s_red2[TPB2];
    __shared__ int eq_buf[1024];
    __shared__ int eq_cnt;
    __shared__ int sel_eq[256];
    __shared__ int s_nsel;

    const int b = blockIdx.x;
    const int t = threadIdx.x;
    float* row = ca + (size_t)b * C;

    int K = *kp;
    if (K < 1) K = 1;
    if (K > 256) K = 256;

    // ---- radix select: exact K-th largest value (as uint key) ----
    unsigned int prefix = 0, pmask = 0;
    int remaining = K;

    for (int pass = 0; pass < 4; ++pass) {
        const int shift = 24 - 8 * pass;
        hist[t] = 0;
        __syncthreads();
        for (int i = t; i < C; i += TPB2) {
            unsigned int k = __float_as_uint(row[i]);
            if ((k & pmask) == prefix)
                atomicAdd(&hist[(k >> shift) & 255u], 1u);
        }
        __syncthreads();
        if (t == 0) {
            int cum = 0;
            int bsel = 0;
            for (int bin = 255; bin >= 0; --bin) {
                int h = (int)hist[bin];
                if (cum + h >= remaining) { bsel = bin; break; }
                cum += h;
            }
            s_bsel = (unsigned)bsel;
            s_cum = cum;
        }
        __syncthreads();
        prefix |= s_bsel << shift;
        pmask  |= 255u << shift;
        remaining -= s_cum;
        __syncthreads();
    }

    const float v32f = __uint_as_float(prefix);  // exact K-th largest value
    const int n_take = remaining;                // # ties (== v32f) to keep, >= 1

    // ---- Pass A: sum of strictly-greater values; collect tie indices ----
    if (t == 0) eq_cnt = 0;
    __syncthreads();
    float sum_gt = 0.0f;
    for (int i = t; i < C; i += TPB2) {
        float v = row[i];
        if (v > v32f) {
            sum_gt += v;
        } else if (v == v32f) {
            int slot = atomicAdd(&eq_cnt, 1);
            if (slot < 1024) eq_buf[slot] = i;
        }
    }
    s_red[t] = sum_gt;
    __syncthreads();
    for (int off = 128; off > 0; off >>= 1) {
        if (t < off) s_red[t] += s_red[t + off];
        __syncthreads();
    }
    const float denom_gt = s_red[0];
    const int n_eq = eq_cnt;

    // ---- choose which ties to keep (lowest indices win, as in lax.top_k) ----
    if (n_eq <= n_take) {
        if (t < n_eq) sel_eq[t] = eq_buf[t];
        if (t == 0) s_nsel = n_eq;
    } else if (n_eq <= 1024) {
        for (int e = t; e < n_eq; e += TPB2) {
            int idx = eq_buf[e];
            int rank = 0;
            for (int j = 0; j < n_eq; ++j) rank += (eq_buf[j] < idx) ? 1 : 0;
            if (rank < n_take) sel_eq[rank] = idx;
        }
        if (t == 0) s_nsel = n_take;
    } else {
        if (t == 0) {  // pathological tie flood: serial fallback
            int cnt = 0;
            for (int i = 0; i < C && cnt < n_take; ++i)
                if (row[i] == v32f) sel_eq[cnt++] = i;
            s_nsel = cnt;
        }
    }
    __syncthreads();
    const int nsel = s_nsel;
    const float denom = denom_gt + (float)nsel * v32f + EPS_DENOM;

    // ---- Pass B: rewrite row in place; accumulate label sums ----
    float lsum = 0.0f, psum = 0.0f;
    for (int i = t; i < C; i += TPB2) {
        float v = row[i];
        float outv = 0.0f;
        bool sel = (v > v32f);
        if (!sel && v == v32f) {
            for (int e = 0; e < nsel; ++e)
                if (sel_eq[e] == i) { sel = true; break; }
        }
        if (sel) {
            outv = v / denom;
            float lab = labels[i];
            lsum += lab;
            psum += outv * lab;
        }
        row[i] = outv;
    }
    s_red[t] = lsum;
    s_red2[t] = psum;
    __syncthreads();
    for (int off = 128; off > 0; off >>= 1) {
        if (t < off) { s_red[t] += s_red[t + off]; s_red2[t] += s_red2[t + off]; }
        __syncthreads();
    }
    if (t == 0) {
        out_mean[b] = s_red[0] / (float)K;
        out_pred[b] = s_red2[0];
    }
}

extern "C" void kernel_launch(void* const* d_in, const int* in_sizes, int n_in,
                              void* d_out, int out_size, void* d_ws, size_t ws_size,
                              hipStream_t stream) {
    const float* q      = (const float*)d_in[0];
    const float* cases  = (const float*)d_in[1];
    const float* labels = (const float*)d_in[2];
    const float* w_fa   = (const float*)d_in[3];
    const float* b_fa   = (const float*)d_in[4];
    const float* w_ca   = (const float*)d_in[5];
    const float* b_ca   = (const float*)d_in[6];
    const int*   kp     = (const int*)d_in[7];

    const int F = in_sizes[3];          // 64
    const int B = in_sizes[0] / F;      // 128
    const int C = in_sizes[1] / F;      // 20000

    float* out      = (float*)d_out;
    const size_t FA = (size_t)B * C * F;
    float* fa_out   = out;
    float* ca_out   = out + FA;
    float* out_mean = ca_out + (size_t)B * C;
    float* out_pred = out_mean + B;

    dim3 gA((C + 15) / 16, B);
    ca_kernel<<<gA, 256, 0, stream>>>(q, cases, w_fa, b_fa, w_ca, b_ca,
                                      ca_out, B, C);
    topk_kernel<<<B, TPB2, 0, stream>>>(ca_out, labels, out_mean, out_pred, C, kp);

    dim3 gB((C + 63) / 64, B);
    fa_kernel<<<gB, 256, 0, stream>>>(q, cases, w_fa, b_fa, fa_out, B, C);
}

// Round 7
// 479.410 us; speedup vs baseline: 1.0033x; 1.0033x over previous
//
#include <hip/hip_runtime.h>
#include <hip/hip_bf16.h>

// B=128, C=20000, F=64, K=32.
// Outputs flat-concat: fa [B*C*64] | ca [B*C] | mean [B] | pred [B], all f32.
//
// Measured component history (this session):
//   topk: plain LDS-atomic radix select ~30 µs (r3/r5); wave-aggregated 465 µs (r4 — NEVER again)
//   ca split kernel: ~35 µs
//   fa: NT stores ~212 µs (r4) vs regular ~415 µs (r6) — NT wins 2x (L2 write-allocate thrash)
//       b-looped case-caching (r5) hurt: fewer/longer blocks -> scattered write window

#define EPS_DENOM 1e-10f

typedef float floatx4 __attribute__((ext_vector_type(4)));

// ---------------------------------------------------------------------------
// Kernel A: case activations only (10 MB out). Numerics verbatim from the
// passing round-1 kernel: 16 lanes per case, per-group dot, shfl-xor tree.
// ---------------------------------------------------------------------------
__global__ __launch_bounds__(256) void ca_kernel(
    const float* __restrict__ q,
    const float* __restrict__ cases,
    const float* __restrict__ w_fa,
    const float* __restrict__ b_fa,
    const float* __restrict__ w_ca,
    const float* __restrict__ b_ca,
    float* __restrict__ ca_out,
    int B, int C)
{
    const int g = threadIdx.x & 15;   // feature group (features g*4 .. g*4+3)
    const int p = threadIdx.x >> 4;   // case slot 0..15
    const int c = blockIdx.x * 16 + p;
    const int b = blockIdx.y;
    if (c >= C) return;

    const int f4 = g * 4;
    const float4 qv = *reinterpret_cast<const float4*>(q     + (size_t)b * 64 + f4);
    const float4 cv = *reinterpret_cast<const float4*>(cases + (size_t)c * 64 + f4);
    const float4 wf = *reinterpret_cast<const float4*>(w_fa + f4);
    const float4 bf = *reinterpret_cast<const float4*>(b_fa + f4);
    const float4 wc = *reinterpret_cast<const float4*>(w_ca + f4);

    float d0 = qv.x - cv.x, d1 = qv.y - cv.y, d2 = qv.z - cv.z, d3 = qv.w - cv.w;
    float s0 = 1.0f / (1.0f + __expf(fmaf(d0 * d0, wf.x, -bf.x)));
    float s1 = 1.0f / (1.0f + __expf(fmaf(d1 * d1, wf.y, -bf.y)));
    float s2 = 1.0f / (1.0f + __expf(fmaf(d2 * d2, wf.z, -bf.z)));
    float s3 = 1.0f / (1.0f + __expf(fmaf(d3 * d3, wf.w, -bf.w)));

    float dot = s0 * wc.x + s1 * wc.y + s2 * wc.z + s3 * wc.w;
    dot += __shfl_xor(dot, 1, 64);
    dot += __shfl_xor(dot, 2, 64);
    dot += __shfl_xor(dot, 4, 64);
    dot += __shfl_xor(dot, 8, 64);

    if (g == 0) {
        float cav = 1.0f / (1.0f + __expf(-(dot + b_ca[0])));
        ca_out[(size_t)b * C + c] = cav;  // raw; topk rewrites in place
    }
}

// ---------------------------------------------------------------------------
// Kernel B: feature_activations streamer — round-4 configuration VERBATIM
// (measured-best: ~212 µs inferred). One query per block, 64 cases per block,
// x-major dispatch (compact sequential write window), NT float4 stores.
// ---------------------------------------------------------------------------
__global__ __launch_bounds__(256) void fa_kernel(
    const float* __restrict__ q,
    const float* __restrict__ cases,
    const float* __restrict__ w_fa,
    const float* __restrict__ b_fa,
    float* __restrict__ fa_out,
    int B, int C)
{
    const int g  = threadIdx.x & 15;
    const int p  = threadIdx.x >> 4;
    const int b  = blockIdx.y;
    const int c0 = blockIdx.x * 64 + p;
    const int f4 = g * 4;

    const float4 qv = *reinterpret_cast<const float4*>(q    + (size_t)b * 64 + f4);
    const float4 wf = *reinterpret_cast<const float4*>(w_fa + f4);
    const float4 bf = *reinterpret_cast<const float4*>(b_fa + f4);

    float4 cv[4];
    #pragma unroll
    for (int j = 0; j < 4; ++j) {
        int c = c0 + j * 16;
        if (c > C - 1) c = C - 1;  // clamp: load stays valid, store is guarded
        cv[j] = *reinterpret_cast<const float4*>(cases + (size_t)c * 64 + f4);
    }

    #pragma unroll
    for (int j = 0; j < 4; ++j) {
        const int c = c0 + j * 16;
        if (c < C) {
            float d0 = qv.x - cv[j].x, d1 = qv.y - cv[j].y;
            float d2 = qv.z - cv[j].z, d3 = qv.w - cv[j].w;
            float s0 = 1.0f / (1.0f + __expf(fmaf(d0 * d0, wf.x, -bf.x)));
            float s1 = 1.0f / (1.0f + __expf(fmaf(d1 * d1, wf.y, -bf.y)));
            float s2 = 1.0f / (1.0f + __expf(fmaf(d2 * d2, wf.z, -bf.z)));
            float s3 = 1.0f / (1.0f + __expf(fmaf(d3 * d3, wf.w, -bf.w)));
            floatx4 sv = { s0, s1, s2, s3 };
            __builtin_nontemporal_store(
                sv, reinterpret_cast<floatx4*>(fa_out + ((size_t)b * C + c) * 64 + f4));
        }
    }
}

// ---------------------------------------------------------------------------
// Kernel C: per-row exact top-K via radix select (plain LDS-atomic histogram),
// then normalize in place + scalar outputs. One block per query row.
// ---------------------------------------------------------------------------
#define TPB2 256

__global__ __launch_bounds__(TPB2) void topk_kernel(
    float* __restrict__ ca,
    const float* __restrict__ labels,
    float* __restrict__ out_mean,
    float* __restrict__ out_pred,
    int C, const int* __restrict__ kp)
{
    __shared__ unsigned int hist[256];
    __shared__ unsigned int s_bsel;
    __shared__ int s_cum;
    __shared__ float s_red[TPB2];
    __shared__ float s_red2[TPB2];
    __shared__ int eq_buf[1024];
    __shared__ int eq_cnt;
    __shared__ int sel_eq[256];
    __shared__ int s_nsel;

    const int b = blockIdx.x;
    const int t = threadIdx.x;
    float* row = ca + (size_t)b * C;

    int K = *kp;
    if (K < 1) K = 1;
    if (K > 256) K = 256;

    // ---- radix select: exact K-th largest value (as uint key) ----
    unsigned int prefix = 0, pmask = 0;
    int remaining = K;

    for (int pass = 0; pass < 4; ++pass) {
        const int shift = 24 - 8 * pass;
        hist[t] = 0;
        __syncthreads();
        for (int i = t; i < C; i += TPB2) {
            unsigned int k = __float_as_uint(row[i]);
            if ((k & pmask) == prefix)
                atomicAdd(&hist[(k >> shift) & 255u], 1u);
        }
        __syncthreads();
        if (t == 0) {
            int cum = 0;
            int bsel = 0;
            for (int bin = 255; bin >= 0; --bin) {
                int h = (int)hist[bin];
                if (cum + h >= remaining) { bsel = bin; break; }
                cum += h;
            }
            s_bsel = (unsigned)bsel;
            s_cum = cum;
        }
        __syncthreads();
        prefix |= s_bsel << shift;
        pmask  |= 255u << shift;
        remaining -= s_cum;
        __syncthreads();
    }

    const float v32f = __uint_as_float(prefix);  // exact K-th largest value
    const int n_take = remaining;                // # ties (== v32f) to keep, >= 1

    // ---- Pass A: sum of strictly-greater values; collect tie indices ----
    if (t == 0) eq_cnt = 0;
    __syncthreads();
    float sum_gt = 0.0f;
    for (int i = t; i < C; i += TPB2) {
        float v = row[i];
        if (v > v32f) {
            sum_gt += v;
        } else if (v == v32f) {
            int slot = atomicAdd(&eq_cnt, 1);
            if (slot < 1024) eq_buf[slot] = i;
        }
    }
    s_red[t] = sum_gt;
    __syncthreads();
    for (int off = 128; off > 0; off >>= 1) {
        if (t < off) s_red[t] += s_red[t + off];
        __syncthreads();
    }
    const float denom_gt = s_red[0];
    const int n_eq = eq_cnt;

    // ---- choose which ties to keep (lowest indices win, as in lax.top_k) ----
    if (n_eq <= n_take) {
        if (t < n_eq) sel_eq[t] = eq_buf[t];
        if (t == 0) s_nsel = n_eq;
    } else if (n_eq <= 1024) {
        for (int e = t; e < n_eq; e += TPB2) {
            int idx = eq_buf[e];
            int rank = 0;
            for (int j = 0; j < n_eq; ++j) rank += (eq_buf[j] < idx) ? 1 : 0;
            if (rank < n_take) sel_eq[rank] = idx;
        }
        if (t == 0) s_nsel = n_take;
    } else {
        if (t == 0) {  // pathological tie flood: serial fallback
            int cnt = 0;
            for (int i = 0; i < C && cnt < n_take; ++i)
                if (row[i] == v32f) sel_eq[cnt++] = i;
            s_nsel = cnt;
        }
    }
    __syncthreads();
    const int nsel = s_nsel;
    const float denom = denom_gt + (float)nsel * v32f + EPS_DENOM;

    // ---- Pass B: rewrite row in place; accumulate label sums ----
    float lsum = 0.0f, psum = 0.0f;
    for (int i = t; i < C; i += TPB2) {
        float v = row[i];
        float outv = 0.0f;
        bool sel = (v > v32f);
        if (!sel && v == v32f) {
            for (int e = 0; e < nsel; ++e)
                if (sel_eq[e] == i) { sel = true; break; }
        }
        if (sel) {
            outv = v / denom;
            float lab = labels[i];
            lsum += lab;
            psum += outv * lab;
        }
        row[i] = outv;
    }
    s_red[t] = lsum;
    s_red2[t] = psum;
    __syncthreads();
    for (int off = 128; off > 0; off >>= 1) {
        if (t < off) { s_red[t] += s_red[t + off]; s_red2[t] += s_red2[t + off]; }
        __syncthreads();
    }
    if (t == 0) {
        out_mean[b] = s_red[0] / (float)K;
        out_pred[b] = s_red2[0];
    }
}

extern "C" void kernel_launch(void* const* d_in, const int* in_sizes, int n_in,
                              void* d_out, int out_size, void* d_ws, size_t ws_size,
                              hipStream_t stream) {
    const float* q      = (const float*)d_in[0];
    const float* cases  = (const float*)d_in[1];
    const float* labels = (const float*)d_in[2];
    const float* w_fa   = (const float*)d_in[3];
    const float* b_fa   = (const float*)d_in[4];
    const float* w_ca   = (const float*)d_in[5];
    const float* b_ca   = (const float*)d_in[6];
    const int*   kp     = (const int*)d_in[7];

    const int F = in_sizes[3];          // 64
    const int B = in_sizes[0] / F;      // 128
    const int C = in_sizes[1] / F;      // 20000

    float* out      = (float*)d_out;
    const size_t FA = (size_t)B * C * F;
    float* fa_out   = out;
    float* ca_out   = out + FA;
    float* out_mean = ca_out + (size_t)B * C;
    float* out_pred = out_mean + B;

    dim3 gA((C + 15) / 16, B);
    ca_kernel<<<gA, 256, 0, stream>>>(q, cases, w_fa, b_fa, w_ca, b_ca,
                                      ca_out, B, C);
    topk_kernel<<<B, TPB2, 0, stream>>>(ca_out, labels, out_mean, out_pred, C, kp);

    dim3 gB((C + 63) / 64, B);
    fa_kernel<<<gB, 256, 0, stream>>>(q, cases, w_fa, b_fa, fa_out, B, C);
}

// Round 8
// 274.705 us; speedup vs baseline: 1.7509x; 1.7452x over previous
//
#include <hip/hip_runtime.h>
#include <hip/hip_bf16.h>

// B=128, C=20000, F=64, K=32.
// Outputs flat-concat: fa [B*C*64] | ca [B*C] | mean [B] | pred [B], all f32.
//
// Measured component history:
//   r3 fused fa_ca = ~182 µs (best fa-path); split ca+fa = ~281 (r4/r6/r7)
//   topk plain radix (global, 256 thr) = ~198 µs  <- THIS round's target
//   topk wave-aggregated = 465 µs (r4, never again)
//   NT vs regular stores: no difference (r6 vs r7)

#define EPS_DENOM 1e-10f

typedef float floatx4 __attribute__((ext_vector_type(4)));

// ---------------------------------------------------------------------------
// Kernel 1 (round-3 verbatim, measured ~182 µs): fused feature_activations
// (NT stores) + unnormalized case activations.
// ---------------------------------------------------------------------------
__global__ __launch_bounds__(256) void fa_ca_kernel(
    const float* __restrict__ q,
    const float* __restrict__ cases,
    const float* __restrict__ w_fa,
    const float* __restrict__ b_fa,
    const float* __restrict__ w_ca,
    const float* __restrict__ b_ca,
    float* __restrict__ fa_out,
    float* __restrict__ ca_out,
    int B, int C)
{
    const int g  = threadIdx.x & 15;   // feature group (features g*4 .. g*4+3)
    const int p  = threadIdx.x >> 4;   // case slot within block (0..15)
    const int b  = blockIdx.y;
    const int c0 = blockIdx.x * 64 + p;
    const int f4 = g * 4;

    const float4 qv = *reinterpret_cast<const float4*>(q    + (size_t)b * 64 + f4);
    const float4 wf = *reinterpret_cast<const float4*>(w_fa + f4);
    const float4 bf = *reinterpret_cast<const float4*>(b_fa + f4);
    const float4 wc = *reinterpret_cast<const float4*>(w_ca + f4);
    const float  bca = b_ca[0];

    #pragma unroll
    for (int j = 0; j < 4; ++j) {
        const int c = c0 + j * 16;
        if (c >= C) break;  // uniform within each 16-lane case group

        const float4 cv = *reinterpret_cast<const float4*>(cases + (size_t)c * 64 + f4);
        float d0 = qv.x - cv.x, d1 = qv.y - cv.y, d2 = qv.z - cv.z, d3 = qv.w - cv.w;
        float s0 = 1.0f / (1.0f + __expf(fmaf(d0 * d0, wf.x, -bf.x)));
        float s1 = 1.0f / (1.0f + __expf(fmaf(d1 * d1, wf.y, -bf.y)));
        float s2 = 1.0f / (1.0f + __expf(fmaf(d2 * d2, wf.z, -bf.z)));
        float s3 = 1.0f / (1.0f + __expf(fmaf(d3 * d3, wf.w, -bf.w)));

        floatx4 sv = { s0, s1, s2, s3 };
        __builtin_nontemporal_store(
            sv, reinterpret_cast<floatx4*>(fa_out + ((size_t)b * C + c) * 64 + f4));

        float dot = s0 * wc.x + s1 * wc.y + s2 * wc.z + s3 * wc.w;
        dot += __shfl_xor(dot, 1, 64);
        dot += __shfl_xor(dot, 2, 64);
        dot += __shfl_xor(dot, 4, 64);
        dot += __shfl_xor(dot, 8, 64);

        if (g == 0) {
            float cav = 1.0f / (1.0f + __expf(-(dot + bca)));
            ca_out[(size_t)b * C + c] = cav;  // raw; topk rewrites in place
        }
    }
}

// ---------------------------------------------------------------------------
// Kernel 2: LDS-resident top-K. One block (1024 thr) per row. Row (80 KB)
// loaded to LDS once; 3x 10-bit radix passes (1024 bins kills the clustered-
// exponent atomic contention); parallel suffix-scan bin selection; final
// normalize+write pass from LDS. Global traffic: 80 KB in + 80 KB out.
// ---------------------------------------------------------------------------
#define TPB3  1024
#define NBINS 1024
#define ROWCAP 20000   // C for this problem; kernel requires C <= ROWCAP

__global__ __launch_bounds__(TPB3) void topk_lds_kernel(
    float* __restrict__ ca,
    const float* __restrict__ labels,
    float* __restrict__ out_mean,
    float* __restrict__ out_pred,
    int C, const int* __restrict__ kp)
{
    __shared__ float row_lds[ROWCAP];
    __shared__ unsigned int hist[NBINS];
    __shared__ unsigned int sc[NBINS];
    __shared__ float s_red[TPB3];
    __shared__ float s_red2[TPB3];
    __shared__ int eq_buf[1024];
    __shared__ int sel_eq[256];
    __shared__ int eq_cnt, s_nsel;
    __shared__ unsigned int s_bsel, s_cum;

    const int b = blockIdx.x;
    const int t = threadIdx.x;
    float* rowg = ca + (size_t)b * C;

    int K = *kp;
    if (K < 1) K = 1;
    if (K > 256) K = 256;

    // ---- load row into LDS (only global read of the row) ----
    for (int i = t; i < C; i += TPB3) row_lds[i] = rowg[i];
    __syncthreads();

    // ---- 3-pass radix select, 10 bits each (keys positive: v in (0,1)) ----
    unsigned int prefix = 0, pmask = 0;
    int remaining = K;

    #pragma unroll
    for (int pass = 0; pass < 3; ++pass) {
        const int shift = 20 - 10 * pass;
        hist[t] = 0;               // t < 1024 == NBINS
        __syncthreads();
        for (int i = t; i < C; i += TPB3) {
            unsigned int k = __float_as_uint(row_lds[i]);
            if ((k & pmask) == prefix)
                atomicAdd(&hist[(k >> shift) & (NBINS - 1u)], 1u);
        }
        __syncthreads();
        // inclusive suffix scan (Hillis-Steele) into sc
        sc[t] = hist[t];
        __syncthreads();
        for (int off = 1; off < NBINS; off <<= 1) {
            unsigned int add = (t + off < NBINS) ? sc[t + off] : 0u;
            __syncthreads();
            sc[t] += add;
            __syncthreads();
        }
        const unsigned int inc = sc[t];            // count of bins >= t
        const unsigned int strict = inc - hist[t]; // count of bins > t
        if ((int)strict < remaining && remaining <= (int)inc) {
            s_bsel = (unsigned)t;
            s_cum = strict;
        }
        __syncthreads();
        prefix |= s_bsel << shift;
        pmask  |= (NBINS - 1u) << shift;
        remaining -= (int)s_cum;
        __syncthreads();
    }

    const float v32f = __uint_as_float(prefix);  // exact K-th largest value
    const int n_take = remaining;                // ties (== v32f) to keep, >= 1

    // ---- Pass A: sum strictly-greater; collect tie indices ----
    if (t == 0) eq_cnt = 0;
    __syncthreads();
    float sum_gt = 0.0f;
    for (int i = t; i < C; i += TPB3) {
        float v = row_lds[i];
        if (v > v32f) {
            sum_gt += v;
        } else if (v == v32f) {
            int slot = atomicAdd(&eq_cnt, 1);
            if (slot < 1024) eq_buf[slot] = i;
        }
    }
    s_red[t] = sum_gt;
    __syncthreads();
    for (int off = TPB3 / 2; off > 0; off >>= 1) {
        if (t < off) s_red[t] += s_red[t + off];
        __syncthreads();
    }
    const float denom_gt = s_red[0];
    const int n_eq = eq_cnt;

    // ---- choose ties to keep: lowest indices (matches lax.top_k) ----
    if (n_eq <= n_take) {
        if (t < n_eq) sel_eq[t] = eq_buf[t];
        if (t == 0) s_nsel = n_eq;
    } else if (n_eq <= 1024) {
        for (int e = t; e < n_eq; e += TPB3) {
            int idx = eq_buf[e];
            int rank = 0;
            for (int j = 0; j < n_eq; ++j) rank += (eq_buf[j] < idx) ? 1 : 0;
            if (rank < n_take) sel_eq[rank] = idx;
        }
        if (t == 0) s_nsel = n_take;
    } else {
        if (t == 0) {  // pathological tie flood: serial fallback (LDS reads)
            int cnt = 0;
            for (int i = 0; i < C && cnt < n_take; ++i)
                if (row_lds[i] == v32f) sel_eq[cnt++] = i;
            s_nsel = cnt;
        }
    }
    __syncthreads();
    const int nsel = s_nsel;
    const float denom = denom_gt + (float)nsel * v32f + EPS_DENOM;

    // ---- Pass B: write final row; accumulate label sums ----
    float lsum = 0.0f, psum = 0.0f;
    for (int i = t; i < C; i += TPB3) {
        float v = row_lds[i];
        float outv = 0.0f;
        bool sel = (v > v32f);
        if (!sel && v == v32f) {
            for (int e = 0; e < nsel; ++e)
                if (sel_eq[e] == i) { sel = true; break; }
        }
        if (sel) {
            outv = v / denom;
            float lab = labels[i];
            lsum += lab;
            psum += outv * lab;
        }
        rowg[i] = outv;
    }
    s_red[t] = lsum;
    s_red2[t] = psum;
    __syncthreads();
    for (int off = TPB3 / 2; off > 0; off >>= 1) {
        if (t < off) { s_red[t] += s_red[t + off]; s_red2[t] += s_red2[t + off]; }
        __syncthreads();
    }
    if (t == 0) {
        out_mean[b] = s_red[0] / (float)K;
        out_pred[b] = s_red2[0];
    }
}

extern "C" void kernel_launch(void* const* d_in, const int* in_sizes, int n_in,
                              void* d_out, int out_size, void* d_ws, size_t ws_size,
                              hipStream_t stream) {
    const float* q      = (const float*)d_in[0];
    const float* cases  = (const float*)d_in[1];
    const float* labels = (const float*)d_in[2];
    const float* w_fa   = (const float*)d_in[3];
    const float* b_fa   = (const float*)d_in[4];
    const float* w_ca   = (const float*)d_in[5];
    const float* b_ca   = (const float*)d_in[6];
    const int*   kp     = (const int*)d_in[7];

    const int F = in_sizes[3];          // 64
    const int B = in_sizes[0] / F;      // 128
    const int C = in_sizes[1] / F;      // 20000

    float* out      = (float*)d_out;
    const size_t FA = (size_t)B * C * F;
    float* fa_out   = out;
    float* ca_out   = out + FA;
    float* out_mean = ca_out + (size_t)B * C;
    float* out_pred = out_mean + B;

    dim3 g1((C + 63) / 64, B);
    fa_ca_kernel<<<g1, 256, 0, stream>>>(q, cases, w_fa, b_fa, w_ca, b_ca,
                                         fa_out, ca_out, B, C);
    topk_lds_kernel<<<B, TPB3, 0, stream>>>(ca_out, labels, out_mean, out_pred,
                                            C, kp);
}

// Round 9
// 251.474 us; speedup vs baseline: 1.9127x; 1.0924x over previous
//
#include <hip/hip_runtime.h>
#include <hip/hip_bf16.h>

// B=128, C=20000, F=64, K=32.
// Outputs flat-concat: fa [B*C*64] | ca [B*C] | mean [B] | pred [B], all f32.
//
// Measured component history:
//   fused fa_ca (r3 form) = ~182 µs  (keep verbatim; numerics passed 7 rounds)
//   topk: global radix 256thr = 198 µs; LDS radix 1024thr (r8) = 92 µs
//   wave-aggregated ballot histogram = 465 µs (r4, never again)
//   NT vs regular stores: identical (r6 vs r7)

#define EPS_DENOM 1e-10f

typedef float floatx4 __attribute__((ext_vector_type(4)));

// ---------------------------------------------------------------------------
// Kernel 1 (round-3 verbatim): fused feature_activations (NT stores) +
// unnormalized case activations.
// ---------------------------------------------------------------------------
__global__ __launch_bounds__(256) void fa_ca_kernel(
    const float* __restrict__ q,
    const float* __restrict__ cases,
    const float* __restrict__ w_fa,
    const float* __restrict__ b_fa,
    const float* __restrict__ w_ca,
    const float* __restrict__ b_ca,
    float* __restrict__ fa_out,
    float* __restrict__ ca_out,
    int B, int C)
{
    const int g  = threadIdx.x & 15;   // feature group (features g*4 .. g*4+3)
    const int p  = threadIdx.x >> 4;   // case slot within block (0..15)
    const int b  = blockIdx.y;
    const int c0 = blockIdx.x * 64 + p;
    const int f4 = g * 4;

    const float4 qv = *reinterpret_cast<const float4*>(q    + (size_t)b * 64 + f4);
    const float4 wf = *reinterpret_cast<const float4*>(w_fa + f4);
    const float4 bf = *reinterpret_cast<const float4*>(b_fa + f4);
    const float4 wc = *reinterpret_cast<const float4*>(w_ca + f4);
    const float  bca = b_ca[0];

    #pragma unroll
    for (int j = 0; j < 4; ++j) {
        const int c = c0 + j * 16;
        if (c >= C) break;  // uniform within each 16-lane case group

        const float4 cv = *reinterpret_cast<const float4*>(cases + (size_t)c * 64 + f4);
        float d0 = qv.x - cv.x, d1 = qv.y - cv.y, d2 = qv.z - cv.z, d3 = qv.w - cv.w;
        float s0 = 1.0f / (1.0f + __expf(fmaf(d0 * d0, wf.x, -bf.x)));
        float s1 = 1.0f / (1.0f + __expf(fmaf(d1 * d1, wf.y, -bf.y)));
        float s2 = 1.0f / (1.0f + __expf(fmaf(d2 * d2, wf.z, -bf.z)));
        float s3 = 1.0f / (1.0f + __expf(fmaf(d3 * d3, wf.w, -bf.w)));

        floatx4 sv = { s0, s1, s2, s3 };
        __builtin_nontemporal_store(
            sv, reinterpret_cast<floatx4*>(fa_out + ((size_t)b * C + c) * 64 + f4));

        float dot = s0 * wc.x + s1 * wc.y + s2 * wc.z + s3 * wc.w;
        dot += __shfl_xor(dot, 1, 64);
        dot += __shfl_xor(dot, 2, 64);
        dot += __shfl_xor(dot, 4, 64);
        dot += __shfl_xor(dot, 8, 64);

        if (g == 0) {
            float cav = 1.0f / (1.0f + __expf(-(dot + bca)));
            ca_out[(size_t)b * C + c] = cav;  // raw; topk rewrites in place
        }
    }
}

// ---------------------------------------------------------------------------
// Kernel 2: LDS-resident top-K, v3.
//  - level-0 histogram fused into the global->LDS load, 8-way privatized with
//    interleaved layout histf[bin*8+priv] (same-bin atomics from different
//    waves hit different banks AND addresses -> no serialization)
//  - suffix scan by wave 0 only (no block barriers inside the scan)
//  - deeper radix levels only if the selected bin is fat (>2048 candidates);
//    otherwise compact candidates and rank via broadcast compare loop
//    (exact JAX tie semantics: value desc, index asc)
// ---------------------------------------------------------------------------
#define TPB3     1024
#define NBINS    1024
#define NPRIV    8
#define CAND_CAP 2048
#define ROWCAP   20000   // requires C <= ROWCAP

__global__ __launch_bounds__(TPB3) void topk_kernel3(
    float* __restrict__ ca,
    const float* __restrict__ labels,
    float* __restrict__ out_mean,
    float* __restrict__ out_pred,
    int C, const int* __restrict__ kp)
{
    __shared__ float    row_lds[ROWCAP];
    __shared__ unsigned histf[NBINS * NPRIV];  // interleaved privatized (lvl 0)
    __shared__ unsigned hist2[NBINS];          // merged / higher-level hist
    __shared__ unsigned sc[NBINS];             // suffix sums
    __shared__ float    s_red[TPB3];
    __shared__ float    s_red2[TPB3];
    __shared__ unsigned cand_key[CAND_CAP];
    __shared__ int      cand_idx[CAND_CAP];
    __shared__ int      s_cand_cnt;
    __shared__ unsigned s_bsel;
    __shared__ int      s_thr_hi, s_thr_lo;

    const int b    = blockIdx.x;
    const int t    = threadIdx.x;
    const int w    = t >> 6;
    const int lane = t & 63;
    float* rowg = ca + (size_t)b * C;

    int K = *kp;
    if (K < 1) K = 1;
    if (K > 256) K = 256;

    // zero privatized histogram
    #pragma unroll
    for (int r = 0; r < NPRIV; ++r) histf[r * NBINS + t] = 0;
    __syncthreads();

    // P1: global->LDS load + level-0 histogram (bins = key>>21; keys positive)
    const int priv = w & (NPRIV - 1);
    for (int i = t; i < C; i += TPB3) {
        float v = rowg[i];
        row_lds[i] = v;
        atomicAdd(&histf[(__float_as_uint(v) >> 21) * NPRIV + priv], 1u);
    }
    __syncthreads();

    // merge privatized copies -> hist2
    {
        unsigned hm = 0;
        #pragma unroll
        for (int r = 0; r < NPRIV; ++r) hm += histf[t * NPRIV + r];
        hist2[t] = hm;
    }
    __syncthreads();

    unsigned prefix = 0, pmask = 0;
    int R = K;            // rank remaining within current prefix set
    int cnt_bin = 0;
    const int shifts[3] = {21, 11, 1};

    for (int lvl = 0; lvl < 3; ++lvl) {
        const int shift = shifts[lvl];
        if (lvl > 0) {
            hist2[t] = 0;
            __syncthreads();
            for (int i = t; i < C; i += TPB3) {
                unsigned key = __float_as_uint(row_lds[i]);
                if ((key & pmask) == prefix)
                    atomicAdd(&hist2[(key >> shift) & (NBINS - 1u)], 1u);
            }
            __syncthreads();
        }
        // suffix scan (sc[b] = count of elems in bins >= b), wave 0 only
        if (w == 0) {
            unsigned v16[16], locsuf[16];
            #pragma unroll
            for (int m = 0; m < 16; ++m) v16[m] = hist2[lane * 16 + m];
            unsigned acc = 0;
            #pragma unroll
            for (int m = 15; m >= 0; --m) { acc += v16[m]; locsuf[m] = acc; }
            const unsigned lanetot = acc;
            unsigned suf = lanetot;
            #pragma unroll
            for (int off = 1; off < 64; off <<= 1) {
                unsigned o = __shfl_down(suf, (unsigned)off, 64);
                if (lane + off < 64) suf += o;
            }
            const unsigned baseh = suf - lanetot;  // sum over lanes > lane
            #pragma unroll
            for (int m = 0; m < 16; ++m) sc[lane * 16 + m] = baseh + locsuf[m];
        }
        __syncthreads();
        {
            unsigned inc    = sc[t];
            unsigned strict = (t < NBINS - 1) ? sc[t + 1] : 0u;
            if ((int)strict < R && R <= (int)inc) s_bsel = (unsigned)t;
        }
        __syncthreads();
        const unsigned bsel       = s_bsel;
        const unsigned strict_sel = (bsel < NBINS - 1) ? sc[bsel + 1] : 0u;
        cnt_bin = (int)(sc[bsel] - strict_sel);
        R      -= (int)strict_sel;
        prefix |= bsel << shift;
        pmask  |= (NBINS - 1u) << shift;
        __syncthreads();
        if (cnt_bin <= CAND_CAP) break;
    }

    const bool tieflood = (cnt_bin > CAND_CAP);  // p ~ 0: >2048 elems within 2 ulp
    float my_selsum = 0.0f;
    bool sel0 = false, sel1 = false;
    unsigned k0 = 0, k1 = 0;
    int i0 = 0x7FFFFFFF, i1 = 0x7FFFFFFF;

    if (!tieflood) {
        if (t == 0) s_cand_cnt = 0;
        __syncthreads();
        // compact candidates + accumulate strictly-greater sum
        for (int i = t; i < C; i += TPB3) {
            float v = row_lds[i];
            unsigned key = __float_as_uint(v);
            unsigned mk  = key & pmask;
            if (mk > prefix) {
                my_selsum += v;
            } else if (mk == prefix) {
                int slot = atomicAdd(&s_cand_cnt, 1);
                if (slot < CAND_CAP) { cand_key[slot] = key; cand_idx[slot] = i; }
            }
        }
        __syncthreads();
        const int n_c = (s_cand_cnt < CAND_CAP) ? s_cand_cnt : CAND_CAP;
        if (t < n_c)        { k0 = cand_key[t];        i0 = cand_idx[t]; }
        if (t + TPB3 < n_c) { k1 = cand_key[t + TPB3]; i1 = cand_idx[t + TPB3]; }
        int r0 = 0, r1 = 0;
        for (int j = 0; j < n_c; ++j) {           // broadcast reads: conflict-free
            unsigned kj = cand_key[j];
            int      ij = cand_idx[j];
            r0 += (kj > k0 || (kj == k0 && ij < i0)) ? 1 : 0;
            r1 += (kj > k1 || (kj == k1 && ij < i1)) ? 1 : 0;
        }
        sel0 = (t < n_c) && (r0 < R);
        sel1 = (t + TPB3 < n_c) && (r1 < R);
        if (sel0) my_selsum += __uint_as_float(k0);
        if (sel1) my_selsum += __uint_as_float(k1);
    } else {
        // all candidates share key bits [30:1]; choose by (bit0 desc, idx asc)
        if (t == 0) {
            int n1 = 0;
            for (int i = 0; i < C; ++i) {
                unsigned key = __float_as_uint(row_lds[i]);
                if ((key & pmask) == prefix && (key & 1u)) n1++;
            }
            int thr_hi = -1, thr_lo = -1;
            if (R <= n1) {
                int cnt = 0;
                for (int i = 0; i < C; ++i) {
                    unsigned key = __float_as_uint(row_lds[i]);
                    if ((key & pmask) == prefix && (key & 1u))
                        if (++cnt == R) { thr_hi = i; break; }
                }
            } else {
                thr_hi = C;
                int need = R - n1, cnt = 0;
                for (int i = 0; i < C; ++i) {
                    unsigned key = __float_as_uint(row_lds[i]);
                    if ((key & pmask) == prefix && !(key & 1u))
                        if (++cnt == need) { thr_lo = i; break; }
                }
            }
            s_thr_hi = thr_hi; s_thr_lo = thr_lo;
        }
        __syncthreads();
        const int thr_hi = s_thr_hi, thr_lo = s_thr_lo;
        for (int i = t; i < C; i += TPB3) {
            float v = row_lds[i];
            unsigned key = __float_as_uint(v);
            unsigned mk  = key & pmask;
            bool sel = (mk > prefix) ||
                       (mk == prefix && ((key & 1u) ? (i <= thr_hi) : (i <= thr_lo)));
            if (sel) my_selsum += v;
        }
    }

    // reduce selected-sum -> denom
    s_red[t] = my_selsum;
    __syncthreads();
    for (int off = TPB3 / 2; off > 0; off >>= 1) {
        if (t < off) s_red[t] += s_red[t + off];
        __syncthreads();
    }
    const float denom = s_red[0] + EPS_DENOM;
    __syncthreads();

    // write pass + label sums
    float lsum = 0.0f, psum = 0.0f;
    const int thr_hi2 = tieflood ? s_thr_hi : 0;
    const int thr_lo2 = tieflood ? s_thr_lo : 0;
    for (int i = t; i < C; i += TPB3) {
        float v = row_lds[i];
        unsigned key = __float_as_uint(v);
        unsigned mk  = key & pmask;
        bool sel = (mk > prefix);
        if (tieflood && !sel && mk == prefix)
            sel = (key & 1u) ? (i <= thr_hi2) : (i <= thr_lo2);
        float outv = 0.0f;
        if (sel) {
            outv = v / denom;
            float lab = labels[i];
            lsum += lab;
            psum += outv * lab;
        }
        rowg[i] = outv;
    }
    __syncthreads();
    if (!tieflood) {   // overwrite selected candidates (write pass put 0 there)
        if (sel0) {
            float ov = __uint_as_float(k0) / denom;
            rowg[i0] = ov;
            float lab = labels[i0];
            lsum += lab; psum += ov * lab;
        }
        if (sel1) {
            float ov = __uint_as_float(k1) / denom;
            rowg[i1] = ov;
            float lab = labels[i1];
            lsum += lab; psum += ov * lab;
        }
    }
    s_red[t]  = lsum;
    s_red2[t] = psum;
    __syncthreads();
    for (int off = TPB3 / 2; off > 0; off >>= 1) {
        if (t < off) { s_red[t] += s_red[t + off]; s_red2[t] += s_red2[t + off]; }
        __syncthreads();
    }
    if (t == 0) {
        out_mean[b] = s_red[0] / (float)K;
        out_pred[b] = s_red2[0];
    }
}

extern "C" void kernel_launch(void* const* d_in, const int* in_sizes, int n_in,
                              void* d_out, int out_size, void* d_ws, size_t ws_size,
                              hipStream_t stream) {
    const float* q      = (const float*)d_in[0];
    const float* cases  = (const float*)d_in[1];
    const float* labels = (const float*)d_in[2];
    const float* w_fa   = (const float*)d_in[3];
    const float* b_fa   = (const float*)d_in[4];
    const float* w_ca   = (const float*)d_in[5];
    const float* b_ca   = (const float*)d_in[6];
    const int*   kp     = (const int*)d_in[7];

    const int F = in_sizes[3];          // 64
    const int B = in_sizes[0] / F;      // 128
    const int C = in_sizes[1] / F;      // 20000

    float* out      = (float*)d_out;
    const size_t FA = (size_t)B * C * F;
    float* fa_out   = out;
    float* ca_out   = out + FA;
    float* out_mean = ca_out + (size_t)B * C;
    float* out_pred = out_mean + B;

    dim3 g1((C + 63) / 64, B);
    fa_ca_kernel<<<g1, 256, 0, stream>>>(q, cases, w_fa, b_fa, w_ca, b_ca,
                                         fa_out, ca_out, B, C);
    topk_kernel3<<<B, TPB3, 0, stream>>>(ca_out, labels, out_mean, out_pred,
                                         C, kp);
}

// Round 10
// 185.835 us; speedup vs baseline: 2.5883x; 1.3532x over previous
//
#include <hip/hip_runtime.h>
#include <hip/hip_bf16.h>

// B=128, C=20000, F=64, K=32.
// Outputs flat-concat: fa [B*C*64] | ca [B*C] | mean [B] | pred [B], all f32.
//
// Measured component history (re-solved r1-r9):
//   fused fa_ca (r3 inline-load structure) = 183 µs   <- reuse lever this round
//   fa split r4-shape (hoisted clamped loads) = 246 µs (hoisting hurt!)
//   fa split b-looped (r5) = 194 µs (b-loop HELPED; earlier claim wrong)
//   topk: plain global radix = 198.6; LDS radix v8 = 92; v9 = 69 µs
//   wave-agg per-value peel histogram = 465 µs (r4) — but single-ballot
//     compaction (no peel) is a different, safe animal.
//   NT vs regular stores: identical.

#define EPS_DENOM 1e-10f

typedef float floatx4 __attribute__((ext_vector_type(4)));

// ---------------------------------------------------------------------------
// Kernel 1: fused feature_activations + case activations, NQ queries/block.
// j-outer / b-inner: cases load stays inline-before-use (r3 structure),
// reused NQ times -> cases HBM re-read traffic / NQ.
// Per-(b,c) arithmetic order identical to r1..r9 (top-k boundary safe).
// ---------------------------------------------------------------------------
#define NQ 4

__global__ __launch_bounds__(256) void fa_ca_kernel(
    const float* __restrict__ q,
    const float* __restrict__ cases,
    const float* __restrict__ w_fa,
    const float* __restrict__ b_fa,
    const float* __restrict__ w_ca,
    const float* __restrict__ b_ca,
    float* __restrict__ fa_out,
    float* __restrict__ ca_out,
    int B, int C)
{
    const int g  = threadIdx.x & 15;   // feature group (features g*4 .. g*4+3)
    const int p  = threadIdx.x >> 4;   // case slot within block (0..15)
    const int b0 = blockIdx.y * NQ;
    const int c0 = blockIdx.x * 64 + p;
    const int f4 = g * 4;

    const float4 wf = *reinterpret_cast<const float4*>(w_fa + f4);
    const float4 bf = *reinterpret_cast<const float4*>(b_fa + f4);
    const float4 wc = *reinterpret_cast<const float4*>(w_ca + f4);
    const float  bca = b_ca[0];

    float4 qv[NQ];
    #pragma unroll
    for (int i = 0; i < NQ; ++i) {
        int bq = b0 + i;
        if (bq > B - 1) bq = B - 1;   // clamp load; writes guarded below
        qv[i] = *reinterpret_cast<const float4*>(q + (size_t)bq * 64 + f4);
    }

    #pragma unroll
    for (int j = 0; j < 4; ++j) {
        const int c = c0 + j * 16;
        if (c >= C) break;  // uniform within each 16-lane case group

        const float4 cv = *reinterpret_cast<const float4*>(cases + (size_t)c * 64 + f4);

        #pragma unroll
        for (int i = 0; i < NQ; ++i) {
            const int b = b0 + i;
            if (b >= B) break;  // block-uniform

            float d0 = qv[i].x - cv.x, d1 = qv[i].y - cv.y;
            float d2 = qv[i].z - cv.z, d3 = qv[i].w - cv.w;
            float s0 = 1.0f / (1.0f + __expf(fmaf(d0 * d0, wf.x, -bf.x)));
            float s1 = 1.0f / (1.0f + __expf(fmaf(d1 * d1, wf.y, -bf.y)));
            float s2 = 1.0f / (1.0f + __expf(fmaf(d2 * d2, wf.z, -bf.z)));
            float s3 = 1.0f / (1.0f + __expf(fmaf(d3 * d3, wf.w, -bf.w)));

            floatx4 sv = { s0, s1, s2, s3 };
            __builtin_nontemporal_store(
                sv, reinterpret_cast<floatx4*>(fa_out + ((size_t)b * C + c) * 64 + f4));

            float dot = s0 * wc.x + s1 * wc.y + s2 * wc.z + s3 * wc.w;
            dot += __shfl_xor(dot, 1, 64);
            dot += __shfl_xor(dot, 2, 64);
            dot += __shfl_xor(dot, 4, 64);
            dot += __shfl_xor(dot, 8, 64);

            if (g == 0) {
                float cav = 1.0f / (1.0f + __expf(-(dot + bca)));
                ca_out[(size_t)b * C + c] = cav;  // raw; topk rewrites in place
            }
        }
    }
}

// ---------------------------------------------------------------------------
// Kernel 2: LDS-resident top-K, v4.
//  vs v3: (a) candidate compaction via single-ballot wave aggregation
//         (1 LDS atomic per wave-batch instead of up to 2048 serialized);
//         (b) block reductions via shfl butterfly + wave-0 finish
//         (4 barriers instead of 20).
// ---------------------------------------------------------------------------
#define TPB3     1024
#define NWAVE    (TPB3 / 64)
#define NBINS    1024
#define NPRIV    8
#define CAND_CAP 2048
#define ROWCAP   20000   // requires C <= ROWCAP

__global__ __launch_bounds__(TPB3) void topk_kernel4(
    float* __restrict__ ca,
    const float* __restrict__ labels,
    float* __restrict__ out_mean,
    float* __restrict__ out_pred,
    int C, const int* __restrict__ kp)
{
    __shared__ float    row_lds[ROWCAP];
    __shared__ unsigned histf[NBINS * NPRIV];  // privatized lvl-0 hist
    __shared__ unsigned hist2[NBINS];
    __shared__ unsigned sc[NBINS];             // suffix sums
    __shared__ unsigned cand_key[CAND_CAP];
    __shared__ int      cand_idx[CAND_CAP];
    __shared__ float    s_wa[NWAVE], s_wb[NWAVE];
    __shared__ float    s_resA, s_resB;
    __shared__ int      s_cand_cnt;
    __shared__ unsigned s_bsel;
    __shared__ int      s_thr_hi, s_thr_lo;

    const int b    = blockIdx.x;
    const int t    = threadIdx.x;
    const int w    = t >> 6;
    const int lane = t & 63;
    float* rowg = ca + (size_t)b * C;

    int K = *kp;
    if (K < 1) K = 1;
    if (K > 256) K = 256;

    #pragma unroll
    for (int r = 0; r < NPRIV; ++r) histf[r * NBINS + t] = 0;
    __syncthreads();

    // P1: global->LDS load + fused level-0 histogram (bin = key>>21)
    const int priv = w & (NPRIV - 1);
    for (int i = t; i < C; i += TPB3) {
        float v = rowg[i];
        row_lds[i] = v;
        atomicAdd(&histf[(__float_as_uint(v) >> 21) * NPRIV + priv], 1u);
    }
    __syncthreads();

    {
        unsigned hm = 0;
        #pragma unroll
        for (int r = 0; r < NPRIV; ++r) hm += histf[t * NPRIV + r];
        hist2[t] = hm;
    }
    __syncthreads();

    unsigned prefix = 0, pmask = 0;
    int R = K;
    int cnt_bin = 0;
    const int shifts[3] = {21, 11, 1};

    for (int lvl = 0; lvl < 3; ++lvl) {
        const int shift = shifts[lvl];
        if (lvl > 0) {
            hist2[t] = 0;
            __syncthreads();
            for (int i = t; i < C; i += TPB3) {
                unsigned key = __float_as_uint(row_lds[i]);
                if ((key & pmask) == prefix)
                    atomicAdd(&hist2[(key >> shift) & (NBINS - 1u)], 1u);
            }
            __syncthreads();
        }
        // suffix scan by wave 0 only
        if (w == 0) {
            unsigned v16[16], locsuf[16];
            #pragma unroll
            for (int m = 0; m < 16; ++m) v16[m] = hist2[lane * 16 + m];
            unsigned acc = 0;
            #pragma unroll
            for (int m = 15; m >= 0; --m) { acc += v16[m]; locsuf[m] = acc; }
            const unsigned lanetot = acc;
            unsigned suf = lanetot;
            #pragma unroll
            for (int off = 1; off < 64; off <<= 1) {
                unsigned o = __shfl_down(suf, (unsigned)off, 64);
                if (lane + off < 64) suf += o;
            }
            const unsigned baseh = suf - lanetot;
            #pragma unroll
            for (int m = 0; m < 16; ++m) sc[lane * 16 + m] = baseh + locsuf[m];
        }
        __syncthreads();
        {
            unsigned inc    = sc[t];
            unsigned strict = (t < NBINS - 1) ? sc[t + 1] : 0u;
            if ((int)strict < R && R <= (int)inc) s_bsel = (unsigned)t;
        }
        __syncthreads();
        const unsigned bsel       = s_bsel;
        const unsigned strict_sel = (bsel < NBINS - 1) ? sc[bsel + 1] : 0u;
        cnt_bin = (int)(sc[bsel] - strict_sel);
        R      -= (int)strict_sel;
        prefix |= bsel << shift;
        pmask  |= (NBINS - 1u) << shift;
        __syncthreads();
        if (cnt_bin <= CAND_CAP) break;
    }

    const bool tieflood = (cnt_bin > CAND_CAP);
    float my_selsum = 0.0f;
    bool sel0 = false, sel1 = false;
    unsigned k0 = 0, k1 = 0;
    int i0 = 0x7FFFFFFF, i1 = 0x7FFFFFFF;

    if (!tieflood) {
        if (t == 0) s_cand_cnt = 0;
        __syncthreads();
        // compact candidates (wave-aggregated: ONE atomic per wave-batch)
        for (int ib = 0; ib < C; ib += TPB3) {
            const int i = ib + t;
            bool is_cand = false;
            unsigned key = 0;
            if (i < C) {
                float v = row_lds[i];
                key = __float_as_uint(v);
                unsigned mk = key & pmask;
                if (mk > prefix)        my_selsum += v;
                else if (mk == prefix)  is_cand = true;
            }
            unsigned long long m = __ballot(is_cand);
            if (m) {
                const int ldr = (int)(__ffsll((unsigned long long)m) - 1);
                int base = 0;
                if (lane == ldr) base = atomicAdd(&s_cand_cnt, __popcll(m));
                base = __shfl(base, ldr, 64);
                if (is_cand) {
                    int pos = base + (int)__popcll(m & ((1ull << lane) - 1ull));
                    if (pos < CAND_CAP) { cand_key[pos] = key; cand_idx[pos] = i; }
                }
            }
        }
        __syncthreads();
        const int n_c = (s_cand_cnt < CAND_CAP) ? s_cand_cnt : CAND_CAP;
        if (t < n_c)        { k0 = cand_key[t];        i0 = cand_idx[t]; }
        if (t + TPB3 < n_c) { k1 = cand_key[t + TPB3]; i1 = cand_idx[t + TPB3]; }
        int r0 = 0, r1 = 0;
        for (int j = 0; j < n_c; ++j) {   // broadcast reads: conflict-free
            unsigned kj = cand_key[j];
            int      ij = cand_idx[j];
            r0 += (kj > k0 || (kj == k0 && ij < i0)) ? 1 : 0;
            r1 += (kj > k1 || (kj == k1 && ij < i1)) ? 1 : 0;
        }
        sel0 = (t < n_c) && (r0 < R);
        sel1 = (t + TPB3 < n_c) && (r1 < R);
        if (sel0) my_selsum += __uint_as_float(k0);
        if (sel1) my_selsum += __uint_as_float(k1);
    } else {
        // all candidates equal in bits [30:1]; pick by (bit0 desc, idx asc)
        if (t == 0) {
            int n1 = 0;
            for (int i = 0; i < C; ++i) {
                unsigned key = __float_as_uint(row_lds[i]);
                if ((key & pmask) == prefix && (key & 1u)) n1++;
            }
            int thr_hi = -1, thr_lo = -1;
            if (R <= n1) {
                int cnt = 0;
                for (int i = 0; i < C; ++i) {
                    unsigned key = __float_as_uint(row_lds[i]);
                    if ((key & pmask) == prefix && (key & 1u))
                        if (++cnt == R) { thr_hi = i; break; }
                }
            } else {
                thr_hi = C;
                int need = R - n1, cnt = 0;
                for (int i = 0; i < C; ++i) {
                    unsigned key = __float_as_uint(row_lds[i]);
                    if ((key & pmask) == prefix && !(key & 1u))
                        if (++cnt == need) { thr_lo = i; break; }
                }
            }
            s_thr_hi = thr_hi; s_thr_lo = thr_lo;
        }
        __syncthreads();
        const int thr_hi = s_thr_hi, thr_lo = s_thr_lo;
        for (int i = t; i < C; i += TPB3) {
            float v = row_lds[i];
            unsigned key = __float_as_uint(v);
            unsigned mk  = key & pmask;
            bool sel = (mk > prefix) ||
                       (mk == prefix && ((key & 1u) ? (i <= thr_hi) : (i <= thr_lo)));
            if (sel) my_selsum += v;
        }
    }

    // reduce selected-sum -> denom (shfl butterfly + wave-0 finish)
    {
        float a = my_selsum;
        #pragma unroll
        for (int off = 1; off < 64; off <<= 1) a += __shfl_xor(a, off, 64);
        if (lane == 0) s_wa[w] = a;
        __syncthreads();
        if (w == 0) {
            float x = (lane < NWAVE) ? s_wa[lane] : 0.0f;
            #pragma unroll
            for (int off = 1; off < NWAVE; off <<= 1) x += __shfl_xor(x, off, 64);
            if (lane == 0) s_resA = x;
        }
        __syncthreads();
    }
    const float denom = s_resA + EPS_DENOM;
    __syncthreads();

    // write pass + label sums
    float lsum = 0.0f, psum = 0.0f;
    const int thr_hi2 = tieflood ? s_thr_hi : 0;
    const int thr_lo2 = tieflood ? s_thr_lo : 0;
    for (int i = t; i < C; i += TPB3) {
        float v = row_lds[i];
        unsigned key = __float_as_uint(v);
        unsigned mk  = key & pmask;
        bool sel = (mk > prefix);
        if (tieflood && !sel && mk == prefix)
            sel = (key & 1u) ? (i <= thr_hi2) : (i <= thr_lo2);
        float outv = 0.0f;
        if (sel) {
            outv = v / denom;
            float lab = labels[i];
            lsum += lab;
            psum += outv * lab;
        }
        rowg[i] = outv;
    }
    __syncthreads();
    if (!tieflood) {   // selected candidates (write pass wrote 0 there)
        if (sel0) {
            float ov = __uint_as_float(k0) / denom;
            rowg[i0] = ov;
            float lab = labels[i0];
            lsum += lab; psum += ov * lab;
        }
        if (sel1) {
            float ov = __uint_as_float(k1) / denom;
            rowg[i1] = ov;
            float lab = labels[i1];
            lsum += lab; psum += ov * lab;
        }
    }
    {
        float a = lsum, bb = psum;
        #pragma unroll
        for (int off = 1; off < 64; off <<= 1) {
            a  += __shfl_xor(a,  off, 64);
            bb += __shfl_xor(bb, off, 64);
        }
        if (lane == 0) { s_wa[w] = a; s_wb[w] = bb; }
        __syncthreads();
        if (w == 0) {
            float x = (lane < NWAVE) ? s_wa[lane] : 0.0f;
            float y = (lane < NWAVE) ? s_wb[lane] : 0.0f;
            #pragma unroll
            for (int off = 1; off < NWAVE; off <<= 1) {
                x += __shfl_xor(x, off, 64);
                y += __shfl_xor(y, off, 64);
            }
            if (lane == 0) {
                out_mean[b] = x / (float)K;
                out_pred[b] = y;
            }
        }
    }
}

extern "C" void kernel_launch(void* const* d_in, const int* in_sizes, int n_in,
                              void* d_out, int out_size, void* d_ws, size_t ws_size,
                              hipStream_t stream) {
    const float* q      = (const float*)d_in[0];
    const float* cases  = (const float*)d_in[1];
    const float* labels = (const float*)d_in[2];
    const float* w_fa   = (const float*)d_in[3];
    const float* b_fa   = (const float*)d_in[4];
    const float* w_ca   = (const float*)d_in[5];
    const float* b_ca   = (const float*)d_in[6];
    const int*   kp     = (const int*)d_in[7];

    const int F = in_sizes[3];          // 64
    const int B = in_sizes[0] / F;      // 128
    const int C = in_sizes[1] / F;      // 20000

    float* out      = (float*)d_out;
    const size_t FA = (size_t)B * C * F;
    float* fa_out   = out;
    float* ca_out   = out + FA;
    float* out_mean = ca_out + (size_t)B * C;
    float* out_pred = out_mean + B;

    dim3 g1((C + 63) / 64, (B + NQ - 1) / NQ);
    fa_ca_kernel<<<g1, 256, 0, stream>>>(q, cases, w_fa, b_fa, w_ca, b_ca,
                                         fa_out, ca_out, B, C);
    topk_kernel4<<<B, TPB3, 0, stream>>>(ca_out, labels, out_mean, out_pred,
                                         C, kp);
}